// Round 10
// baseline (2885.739 us; speedup 1.0000x reference)
//
#include <hip/hip_runtime.h>
#include <math.h>

#define B_ 64
#define T_ 2048
#define E_ 128
#define H_ 128
#define G3_ 384   // 3*H
#define C_ 32
#define M_ (T_ * B_)   // 131072 tokens

typedef _Float16 f16x2 __attribute__((ext_vector_type(2)));

__device__ __forceinline__ f16x2 as_h2(unsigned int u) {
    union { unsigned int u; f16x2 h; } c; c.u = u; return c.h;
}

#if __has_builtin(__builtin_amdgcn_fdot2)
__device__ __forceinline__ float fdot2_acc(f16x2 a, f16x2 b, float c) {
    return __builtin_amdgcn_fdot2(a, b, c, false);
}
#else
__device__ __forceinline__ float fdot2_acc(f16x2 a, f16x2 b, float c) {
    return fmaf((float)a.y, (float)b.y, fmaf((float)a.x, (float)b.x, c));
}
#endif

// ---------------------------------------------------------------------------
// K1: gi[m][r] = bias[r] + dot(w[r][:], emb[x]) ; m = t*B + b  (layer-0 only;
// layer-1 input gates are fused into gru_fused). 384 threads, one output row
// per thread (64 weight VGPRs).
// ---------------------------------------------------------------------------
template <bool GATHER>
__global__ __launch_bounds__(384, 1) void gates_gemm(
    const float* __restrict__ src,   // emb [V,128]
    const int*   __restrict__ xidx,  // x [B,T]
    const float* __restrict__ w,     // [384,128]
    const float* __restrict__ bias,  // [384]
    float* __restrict__ gi)          // [M,384]
{
    const int r = threadIdx.x;  // output row 0..383
    f16x2 wr[64];
    {
        const float2* w2 = (const float2*)(w + (long)r * 128);
#pragma unroll
        for (int i = 0; i < 64; i++) {
            float2 v = w2[i];
            wr[i] = (f16x2){(_Float16)v.x, (_Float16)v.y};
        }
    }
    const float br = bias[r];

    __shared__ __align__(16) f16x2 rows[8][64];   // 8 tokens x 128 f16

    for (int grp = blockIdx.x; grp < M_ / 8; grp += gridDim.x) {
        const int m0 = grp * 8;
        __syncthreads();  // protect rows[] from readers of previous iter
        for (int j = r; j < 512; j += 384) {
            const int s = j >> 6;               // token in group
            const int p = j & 63;               // f16x2 pair within row
            const int mm = m0 + s;
            long row;
            if (GATHER) {
                const int t = mm >> 6;          // m = t*B + b, B=64
                const int bb = mm & 63;
                row = (long)xidx[bb * T_ + t];
            } else {
                row = mm;
            }
            float2 v = ((const float2*)(src + row * 128))[p];
            rows[s][p] = (f16x2){(_Float16)v.x, (_Float16)v.y};
        }
        __syncthreads();
        for (int s = 0; s < 8; s++) {
            const uint4* h16 = (const uint4*)rows[s];
            float a0 = br, a1 = 0.f, a2 = 0.f, a3 = 0.f;
#pragma unroll
            for (int i = 0; i < 16; i++) {
                uint4 u = h16[i];
                a0 = fdot2_acc(wr[4*i+0], as_h2(u.x), a0);
                a1 = fdot2_acc(wr[4*i+1], as_h2(u.y), a1);
                a2 = fdot2_acc(wr[4*i+2], as_h2(u.z), a2);
                a3 = fdot2_acc(wr[4*i+3], as_h2(u.w), a3);
            }
            gi[(long)(m0 + s) * G3_ + r] = (a0 + a1) + (a2 + a3);
        }
    }
}

// ---------------------------------------------------------------------------
// K2: FUSED two-layer GRU recurrence.
// One block per batch, 768 threads = 12 waves (3/SIMD TLP from the single
// resident workgroup).
// Round-10 change: __launch_bounds__(768, 1). r8's (768,3) and r9's
// waves_per_eu(3,3) both produced an 84-VGPR budget (≈6 waves/EU target)
// and spilled the 96-VGPR weight array to scratch (WRITE_SIZE +11.9 MB =
// 64x768x~63 spilled dwords; ~60 scratch reloads/thread/step = the
// 2935-cyc/step cost). r7's (256,1) got 104 VGPRs with the same 96-reg
// weight set — min-occupancy 1 leaves the allocator's budget open (we only
// run 64 blocks = 1/CU, so budgeting for 1 wave/EU is harmless).
// Everything else identical to round 8.
// ---------------------------------------------------------------------------
#define HB0(S) (lds + (S) * 320)
#define Y0R(S) (lds + 640 + (S) * 320)
#define HB1(S) (lds + 1280 + (S) * 320)

#define DOT96(HSRC, S0, S1, S2)                                                \
  {                                                                            \
    float a00 = 0.f, a01 = 0.f, a10 = 0.f, a11 = 0.f, a20 = 0.f, a21 = 0.f;    \
    _Pragma("unroll")                                                          \
    for (int i = 0; i < 8; i++) {                                              \
      uint4 u = (HSRC)[i];                                                     \
      f16x2 ux = as_h2(u.x), uy = as_h2(u.y), uz = as_h2(u.z), uw = as_h2(u.w);\
      a00 = fdot2_acc(wr[0][4*i+0], ux, a00);                                  \
      a10 = fdot2_acc(wr[1][4*i+0], ux, a10);                                  \
      a20 = fdot2_acc(wr[2][4*i+0], ux, a20);                                  \
      a01 = fdot2_acc(wr[0][4*i+1], uy, a01);                                  \
      a11 = fdot2_acc(wr[1][4*i+1], uy, a11);                                  \
      a21 = fdot2_acc(wr[2][4*i+1], uy, a21);                                  \
      a00 = fdot2_acc(wr[0][4*i+2], uz, a00);                                  \
      a10 = fdot2_acc(wr[1][4*i+2], uz, a10);                                  \
      a20 = fdot2_acc(wr[2][4*i+2], uz, a20);                                  \
      a01 = fdot2_acc(wr[0][4*i+3], uw, a01);                                  \
      a11 = fdot2_acc(wr[1][4*i+3], uw, a11);                                  \
      a21 = fdot2_acc(wr[2][4*i+3], uw, a21);                                  \
    }                                                                          \
    S0 = a00 + a01; S1 = a10 + a11; S2 = a20 + a21;                            \
  }

#define FSTEP(SP, TT, IR, IZ, INN)                                             \
  {                                                                            \
    if (isL0) {                                                                \
      if ((TT) < T_) {                                                         \
        const uint4* hsrc = (const uint4*)(HB0(SP) + ksel * 160);              \
        float s0, s1, s2;                                                      \
        DOT96(hsrc, s0, s1, s2);                                               \
        const float hr = s0 + __shfl_xor(s0, 1) + c0;                          \
        const float hz = s1 + __shfl_xor(s1, 1) + c1;                          \
        const float hn = s2 + __shfl_xor(s2, 1) + cn_h;                        \
        const float rr = 1.f / (1.f + __expf(-((IR) + hr)));                   \
        const float zz = 1.f / (1.f + __expf(-((IZ) + hz)));                   \
        const float na = (INN) + rr * hn;                                      \
        const float nn = 1.f - 2.f / (__expf(2.f * na) + 1.f);                 \
        h_own = (1.f - zz) * nn + zz * h_own;                                  \
        char* wb = (ksel == 0) ? HB0((SP) ^ 1) : Y0R(SP);                      \
        *(_Float16*)(wb + ((g >> 6) * 160) + ((g & 63) * 2)) = (_Float16)h_own;\
        const int tp = ((TT) + 2 < T_) ? (TT) + 2 : (TT);                      \
        const float* gp = gi_g + (size_t)tp * (B_ * G3_);                      \
        IR = gp[0]; IZ = gp[128]; INN = gp[256];                               \
      }                                                                        \
    } else {                                                                   \
      if ((TT) > 0) {                                                          \
        const char* base = (ksel < 2) ? Y0R((SP) ^ 1) : HB1(SP);               \
        const uint4* hsrc = (const uint4*)(base + (ksel & 1) * 160);           \
        float s0, s1, s2;                                                      \
        DOT96(hsrc, s0, s1, s2);                                               \
        const float u0 = s0 + __shfl_xor(s0, 1);                               \
        const float u1 = s1 + __shfl_xor(s1, 1);                               \
        const float u2 = s2 + __shfl_xor(s2, 1);                               \
        const float v0 = __shfl_xor(u0, 2);                                    \
        const float v1 = __shfl_xor(u1, 2);                                    \
        const float v2 = __shfl_xor(u2, 2);                                    \
        const float rr = 1.f / (1.f + __expf(-(u0 + v0 + c0)));                \
        const float zz = 1.f / (1.f + __expf(-(u1 + v1 + c1)));                \
        const float inn = (ksel < 2) ? u2 : v2;                                \
        const float hnn = (ksel < 2) ? v2 : u2;                                \
        const float na = inn + cn_i + rr * (hnn + cn_h);                       \
        const float nn = 1.f - 2.f / (__expf(2.f * na) + 1.f);                 \
        h_own = (1.f - zz) * nn + zz * h_own;                                  \
        if (ksel == 0)                                                         \
          *(_Float16*)(HB1((SP) ^ 1) + ((g >> 6) * 160) + ((g & 63) * 2)) =    \
              (_Float16)h_own;                                                 \
        if (ksel == 1)                                                         \
          y[((size_t)((TT) - 1) * B_ + b) * H_ + g] = h_own;                   \
      }                                                                        \
    }                                                                          \
    asm volatile("s_waitcnt lgkmcnt(0)" ::: "memory");                         \
    __builtin_amdgcn_s_barrier();                                              \
    __builtin_amdgcn_sched_barrier(0);                                         \
  }

__global__ __launch_bounds__(768, 1) void gru_fused(
    const float* __restrict__ gi,     // [M,384]  layer-0 input gates
    const float* __restrict__ w_hh0,  // [384,128]
    const float* __restrict__ b_hh0,  // [384]
    const float* __restrict__ w_ih1,  // [384,128]
    const float* __restrict__ w_hh1,  // [384,128]
    const float* __restrict__ b_ih1,  // [384]
    const float* __restrict__ b_hh1,  // [384]
    float* __restrict__ y)            // [M,128]  layer-1 output (t*B+b major)
{
    const int tid = threadIdx.x;
    const int wv  = tid >> 6;
    const int l   = tid & 63;
    const int b   = blockIdx.x;
    const bool isL0 = (wv < 4);

    int g, ksel;
    const float* wsrc;
    if (isL0) {
        g = wv * 32 + (l >> 1);      // h0-dim (pair-shared)
        ksel = l & 1;                // K-half of h0
        wsrc = w_hh0;
    } else {
        const int idx = (wv - 4) * 64 + l;   // 0..511
        g = idx >> 2;                // h1-dim (quad-shared)
        ksel = idx & 3;              // quad: 0,1 = y0-part; 2,3 = h1-part
        wsrc = (ksel < 2) ? w_ih1 : w_hh1;
    }
    const int kwin = (isL0 ? ksel : (ksel & 1)) * 64;

    // weights: rows {g, g+128, g+256}, K-window [kwin, kwin+64)
    f16x2 wr[3][32];
#pragma unroll
    for (int G = 0; G < 3; G++) {
        const float2* w2 = (const float2*)(wsrc + (size_t)(g + 128 * G) * 128 + kwin);
#pragma unroll
        for (int i = 0; i < 32; i++) {
            float2 v = w2[i];
            wr[G][i] = (f16x2){(_Float16)v.x, (_Float16)v.y};
        }
    }
    // biases: L0: c0,c1 = b_hh0 r/z; cn_h = b_hh0 n (gi already has b_ih0).
    //         L1: c0,c1 = b_ih1+b_hh1 r/z; cn_i = b_ih1 n; cn_h = b_hh1 n.
    float c0, c1, cn_i, cn_h;
    if (isL0) {
        c0 = b_hh0[g]; c1 = b_hh0[g + 128]; cn_i = 0.f; cn_h = b_hh0[g + 256];
    } else {
        c0 = b_ih1[g] + b_hh1[g];
        c1 = b_ih1[g + 128] + b_hh1[g + 128];
        cn_i = b_ih1[g + 256];
        cn_h = b_hh1[g + 256];
    }

    // LDS: hb0[2] | y0ring[2] | hb1[2]; each slot = 2 windows x 160 B
    __shared__ __align__(16) char lds[1920];
    if (tid < 120) ((uint4*)lds)[tid] = (uint4){0, 0, 0, 0};

    float h_own = 0.f;

    const float* gi_g = gi + (size_t)b * G3_ + g;

    // gi0 prefetch (L0 only): t=0 -> A set, t=1 -> B set
    float irA = 0.f, izA = 0.f, innA = 0.f, irB = 0.f, izB = 0.f, innB = 0.f;
    if (isL0) {
        irA = gi_g[0]; izA = gi_g[128]; innA = gi_g[256];
        const float* p1 = gi_g + (size_t)(B_ * G3_);
        irB = p1[0]; izB = p1[128]; innB = p1[256];
    }

    __syncthreads();  // one-time full drain: LDS zero-init visible

    for (int t = 0; t < T_; t += 2) {
        FSTEP(0, t,     irA, izA, innA)
        FSTEP(1, t + 1, irB, izB, innB)
    }
    FSTEP(0, T_, irA, izA, innA)   // step 2048: L0 idle, L1 finishes h1[2047]
}

// ---------------------------------------------------------------------------
// K5: out[b*T+t][c] = relu(fc_b[c] + dot(fc_w[c], y[t*B+b]))
// ---------------------------------------------------------------------------
__global__ __launch_bounds__(256, 2) void fc_relu(
    const float* __restrict__ y,     // [M,128]
    const float* __restrict__ fc_w,  // [32,128]
    const float* __restrict__ fc_b,  // [32]
    float* __restrict__ out)         // [B*T,32]
{
    const int tid = threadIdx.x;
    const int c = tid & 31;
    const int slot = tid >> 5;

    float4 wr[32];
    const float4* w4 = (const float4*)(fc_w + c * 128);
#pragma unroll
    for (int i = 0; i < 32; i++) wr[i] = w4[i];
    const float bc = fc_b[c];

    __shared__ __align__(16) float rows[8][128];

    for (int grp = blockIdx.x; grp < M_ / 8; grp += gridDim.x) {
        const int m0 = grp * 8;
        __syncthreads();
        for (int i = tid; i < 8 * 128; i += 256) {
            rows[i >> 7][i & 127] = y[(long)m0 * 128 + i];
        }
        __syncthreads();
        const float4* h4 = (const float4*)rows[slot];
        float a0 = bc, a1 = 0.f, a2 = 0.f, a3 = 0.f;
#pragma unroll
        for (int i = 0; i < 32; i += 4) {
            float4 h0 = h4[i], h1 = h4[i + 1], h2 = h4[i + 2], h3 = h4[i + 3];
            a0 = fmaf(wr[i].w, h0.w, fmaf(wr[i].z, h0.z, fmaf(wr[i].y, h0.y, fmaf(wr[i].x, h0.x, a0))));
            a1 = fmaf(wr[i+1].w, h1.w, fmaf(wr[i+1].z, h1.z, fmaf(wr[i+1].y, h1.y, fmaf(wr[i+1].x, h1.x, a1))));
            a2 = fmaf(wr[i+2].w, h2.w, fmaf(wr[i+2].z, h2.z, fmaf(wr[i+2].y, h2.y, fmaf(wr[i+2].x, h2.x, a2))));
            a3 = fmaf(wr[i+3].w, h3.w, fmaf(wr[i+3].z, h3.z, fmaf(wr[i+3].y, h3.y, fmaf(wr[i+3].x, h3.x, a3))));
        }
        float acc = (a0 + a1) + (a2 + a3);
        acc = fmaxf(acc, 0.f);
        const int m = m0 + slot;
        const int t = m >> 6;
        const int b = m & 63;
        out[((long)b * T_ + t) * C_ + c] = acc;
    }
}

// ---------------------------------------------------------------------------
extern "C" void kernel_launch(void* const* d_in, const int* in_sizes, int n_in,
                              void* d_out, int out_size, void* d_ws, size_t ws_size,
                              hipStream_t stream) {
    const int*   x     = (const int*)d_in[0];
    const float* emb   = (const float*)d_in[1];
    const float* w_ih0 = (const float*)d_in[2];
    const float* w_hh0 = (const float*)d_in[3];
    const float* b_ih0 = (const float*)d_in[4];
    const float* b_hh0 = (const float*)d_in[5];
    const float* w_ih1 = (const float*)d_in[6];
    const float* w_hh1 = (const float*)d_in[7];
    const float* b_ih1 = (const float*)d_in[8];
    const float* b_hh1 = (const float*)d_in[9];
    const float* fc_w  = (const float*)d_in[10];
    const float* fc_b  = (const float*)d_in[11];
    float* out = (float*)d_out;

    // workspace: gi0 [M,384] fp32 (201.3 MB) + y1 [M,128] fp32 (67.1 MB)
    float* gi = (float*)d_ws;
    float* yb = (float*)((char*)d_ws + (size_t)M_ * G3_ * sizeof(float));

    // layer 0 input gates (embedding gather fused)
    gates_gemm<true><<<512, 384, 0, stream>>>(emb, x, w_ih0, b_ih0, gi);
    // FUSED: layer-0 recurrence + layer-1 input gates + layer-1 recurrence
    gru_fused<<<B_, 768, 0, stream>>>(gi, w_hh0, b_hh0, w_ih1, w_hh1, b_ih1, b_hh1, yb);
    // FC + ReLU
    fc_relu<<<512, 256, 0, stream>>>(yb, fc_w, fc_b, out);
}

// Round 11
// 1704.395 us; speedup vs baseline: 1.6931x; 1.6931x over previous
//
#include <hip/hip_runtime.h>
#include <math.h>

#define B_ 64
#define T_ 2048
#define E_ 128
#define H_ 128
#define G3_ 384   // 3*H
#define C_ 32
#define M_ (T_ * B_)   // 131072 tokens
#define CH_ 16         // pipeline chunk (steps)
#define NCH_ (T_ / CH_)

typedef _Float16 f16x2 __attribute__((ext_vector_type(2)));

__device__ __forceinline__ f16x2 as_h2(unsigned int u) {
    union { unsigned int u; f16x2 h; } c; c.u = u; return c.h;
}

#if __has_builtin(__builtin_amdgcn_fdot2)
__device__ __forceinline__ float fdot2_acc(f16x2 a, f16x2 b, float c) {
    return __builtin_amdgcn_fdot2(a, b, c, false);
}
#else
__device__ __forceinline__ float fdot2_acc(f16x2 a, f16x2 b, float c) {
    return fmaf((float)a.y, (float)b.y, fmaf((float)a.x, (float)b.x, c));
}
#endif

__device__ __forceinline__ void wait_ge(int* f, int need) {
    while (__hip_atomic_load(f, __ATOMIC_ACQUIRE, __HIP_MEMORY_SCOPE_AGENT) < need)
        __builtin_amdgcn_s_sleep(8);
}

// ---------------------------------------------------------------------------
// K1: gi0[m][r] = b_ih0[r] + dot(w_ih0[r], emb[x]) ; m = t*B + b
// 384 threads, one output row per thread (64 weight VGPRs). Unchanged.
// ---------------------------------------------------------------------------
template <bool GATHER>
__global__ __launch_bounds__(384, 1) void gates_gemm(
    const float* __restrict__ src,   // emb [V,128]
    const int*   __restrict__ xidx,  // x [B,T]
    const float* __restrict__ w,     // [384,128]
    const float* __restrict__ bias,  // [384]
    float* __restrict__ gi)          // [M,384]
{
    const int r = threadIdx.x;  // output row 0..383
    f16x2 wr[64];
    {
        const float2* w2 = (const float2*)(w + (long)r * 128);
#pragma unroll
        for (int i = 0; i < 64; i++) {
            float2 v = w2[i];
            wr[i] = (f16x2){(_Float16)v.x, (_Float16)v.y};
        }
    }
    const float br = bias[r];

    __shared__ __align__(16) f16x2 rows[8][64];   // 8 tokens x 128 f16

    for (int grp = blockIdx.x; grp < M_ / 8; grp += gridDim.x) {
        const int m0 = grp * 8;
        __syncthreads();  // protect rows[] from readers of previous iter
        for (int j = r; j < 512; j += 384) {
            const int s = j >> 6;               // token in group
            const int p = j & 63;               // f16x2 pair within row
            const int mm = m0 + s;
            long row;
            if (GATHER) {
                const int t = mm >> 6;          // m = t*B + b, B=64
                const int bb = mm & 63;
                row = (long)xidx[bb * T_ + t];
            } else {
                row = mm;
            }
            float2 v = ((const float2*)(src + row * 128))[p];
            rows[s][p] = (f16x2){(_Float16)v.x, (_Float16)v.y};
        }
        __syncthreads();
        for (int s = 0; s < 8; s++) {
            const uint4* h16 = (const uint4*)rows[s];
            float a0 = br, a1 = 0.f, a2 = 0.f, a3 = 0.f;
#pragma unroll
            for (int i = 0; i < 16; i++) {
                uint4 u = h16[i];
                a0 = fdot2_acc(wr[4*i+0], as_h2(u.x), a0);
                a1 = fdot2_acc(wr[4*i+1], as_h2(u.y), a1);
                a2 = fdot2_acc(wr[4*i+2], as_h2(u.z), a2);
                a3 = fdot2_acc(wr[4*i+3], as_h2(u.w), a3);
            }
            gi[(long)(m0 + s) * G3_ + r] = (a0 + a1) + (a2 + a3);
        }
    }
}

// ---------------------------------------------------------------------------
// K2: 3-stage cross-block GRU pipeline (round 11).
// 192 blocks x 256 threads (all <=256-thread proven register configs;
// the 768-thread fused kernel was clamped to 84 VGPRs and spilled).
//   blocks [0,64):    L0 recurrence, batch b (r7 structure, 96 weight VGPRs)
//                     reads gi0, writes y0 -> ybuf, releases p0[b] per chunk.
//   blocks [64,128):  GEMM stage: gi1[t] = b_ih1 + W_ih1 . y0[t], written
//                     IN-PLACE over consumed gi0 rows (ws stays 268 MB);
//                     waits p0[b] >= (c+1)*CH, releases p1[b] = c+1.
//   blocks [128,192): L1 recurrence on gi1/w_hh1 (same r7 structure), waits
//                     p1[b] >= c+2 (covers 2-step gi prefetch into chunk
//                     c+1), writes y1 over y0 (safe: GEMM consumed y0[t,b]
//                     before releasing the chunk L1 waits on).
// Flags (p0[64], p1[64]) live in d_out (memset'd before launch; fc_relu
// overwrites d_out afterwards). Release/acquire via __hip_atomic_* AGENT
// scope (cross-XCD L2 visibility). Flags are monotone -> no deadlock.
// 192 blocks < 256 CUs -> all co-resident; pipeline fill ~2 chunks.
// ---------------------------------------------------------------------------
#define DOT96(HSRC, S0, S1, S2)                                                \
  {                                                                            \
    float a00 = 0.f, a01 = 0.f, a10 = 0.f, a11 = 0.f, a20 = 0.f, a21 = 0.f;    \
    _Pragma("unroll")                                                          \
    for (int i = 0; i < 8; i++) {                                              \
      uint4 u = (HSRC)[i];                                                     \
      f16x2 ux = as_h2(u.x), uy = as_h2(u.y), uz = as_h2(u.z), uw = as_h2(u.w);\
      a00 = fdot2_acc(wr[0][4*i+0], ux, a00);                                  \
      a10 = fdot2_acc(wr[1][4*i+0], ux, a10);                                  \
      a20 = fdot2_acc(wr[2][4*i+0], ux, a20);                                  \
      a01 = fdot2_acc(wr[0][4*i+1], uy, a01);                                  \
      a11 = fdot2_acc(wr[1][4*i+1], uy, a11);                                  \
      a21 = fdot2_acc(wr[2][4*i+1], uy, a21);                                  \
      a00 = fdot2_acc(wr[0][4*i+2], uz, a00);                                  \
      a10 = fdot2_acc(wr[1][4*i+2], uz, a10);                                  \
      a20 = fdot2_acc(wr[2][4*i+2], uz, a20);                                  \
      a01 = fdot2_acc(wr[0][4*i+3], uw, a01);                                  \
      a11 = fdot2_acc(wr[1][4*i+3], uw, a11);                                  \
      a21 = fdot2_acc(wr[2][4*i+3], uw, a21);                                  \
    }                                                                          \
    S0 = a00 + a01; S1 = a10 + a11; S2 = a20 + a21;                            \
  }

#define GSTEPX(CUR, NXT, IR, IZ, INN, TT, TP)                                  \
  {                                                                            \
    const uint4* hsrc = (const uint4*)((const char*)hb[CUR] + kh * 128);       \
    float s0, s1, s2;                                                          \
    DOT96(hsrc, s0, s1, s2);                                                   \
    const float hr = s0 + __shfl_xor(s0, 1) + bg0;                             \
    const float hz = s1 + __shfl_xor(s1, 1) + bg1;                             \
    const float hn = s2 + __shfl_xor(s2, 1) + bg2;                             \
    const float rr = 1.f / (1.f + __expf(-((IR) + hr)));                       \
    const float zz = 1.f / (1.f + __expf(-((IZ) + hz)));                       \
    const float na = (INN) + rr * hn;                                          \
    const float nn = 1.f - 2.f / (__expf(2.f * na) + 1.f);                     \
    h_own = (1.f - zz) * nn + zz * h_own;                                      \
    if (kh == 0) hb[NXT][g] = (_Float16)h_own;                                 \
    else         y_g[(size_t)(TT) * (B_ * H_)] = h_own;                        \
    {                                                                          \
      const int tp = ((TP) < T_) ? (TP) : (TT);                                \
      const float* gp = gi_g + (size_t)tp * (B_ * G3_);                        \
      IR = gp[0]; IZ = gp[128]; INN = gp[256];                                 \
    }                                                                          \
    asm volatile("s_waitcnt lgkmcnt(0)" ::: "memory");                         \
    __builtin_amdgcn_s_barrier();                                              \
    __builtin_amdgcn_sched_barrier(0);                                         \
  }

__global__ __launch_bounds__(256, 1) void gru_pipe(
    float* __restrict__ gi,           // [M,384] gi0, overwritten in-place by gi1
    const float* __restrict__ w_hh0,  // [384,128]
    const float* __restrict__ b_hh0,  // [384]
    const float* __restrict__ w_ih1,  // [384,128]
    const float* __restrict__ b_ih1,  // [384]
    const float* __restrict__ w_hh1,  // [384,128]
    const float* __restrict__ b_hh1,  // [384]
    float* __restrict__ ybuf,         // [M,128] y0 then y1 (shared, flag-ordered)
    int* __restrict__ flags)          // p0[64] | p1[64]  (in d_out)
{
    const int tid = threadIdx.x;
    const int w   = tid >> 6;        // wave 0..3
    const int l   = tid & 63;
    const int g   = w * 32 + (l >> 1);   // owned dim (pair-shared)
    const int kh  = l & 1;               // K-half
    const int role = blockIdx.x >> 6;    // 0=L0, 1=GEMM, 2=L1
    const int b    = blockIdx.x & 63;
    int* p0 = flags + b;
    int* p1 = flags + 64 + b;

    __shared__ __align__(16) _Float16 hb[2][128];   // recurrence h dbuf
    __shared__ __align__(16) f16x2 yrow[16][64];    // GEMM: 16 staged y0 rows

    if (role == 1) {
        // ------------------- GEMM stage: gi1 = b_ih1 + W_ih1 . y0 ---------
        f16x2 wr[3][32];
#pragma unroll
        for (int G = 0; G < 3; G++) {
            const float2* w2 = (const float2*)(w_ih1 + (size_t)(g + 128 * G) * 128 + kh * 64);
#pragma unroll
            for (int i = 0; i < 32; i++) {
                float2 v = w2[i];
                wr[G][i] = (f16x2){(_Float16)v.x, (_Float16)v.y};
            }
        }
        const float c0 = b_ih1[g], c1 = b_ih1[g + 128], c2 = b_ih1[g + 256];

        for (int c = 0; c < NCH_; c++) {
            if (tid == 0) wait_ge(p0, (c + 1) * CH_);
            __syncthreads();   // all threads see chunk-ready; also protects yrow
            // stage 16 y0 rows (tokens t = c*16+s of this batch) as f16
            for (int j = tid; j < 16 * 64; j += 256) {
                const int s = j >> 6, p = j & 63;
                const float2 v = ((const float2*)(ybuf +
                    ((size_t)(c * CH_ + s) * B_ + b) * H_))[p];
                yrow[s][p] = (f16x2){(_Float16)v.x, (_Float16)v.y};
            }
            __syncthreads();
            for (int s = 0; s < 16; s++) {
                const uint4* hsrc = (const uint4*)yrow[s] + kh * 8;
                float s0, s1, s2;
                DOT96(hsrc, s0, s1, s2);
                const float r0v = s0 + __shfl_xor(s0, 1);
                const float r1v = s1 + __shfl_xor(s1, 1);
                const float r2v = s2 + __shfl_xor(s2, 1);
                if (kh == 0) {
                    float* go = gi + ((size_t)(c * CH_ + s) * B_ + b) * G3_ + g;
                    go[0]   = r0v + c0;
                    go[128] = r1v + c1;
                    go[256] = r2v + c2;
                }
            }
            asm volatile("s_waitcnt vmcnt(0)" ::: "memory");  // gi1 stores done
            __syncthreads();
            if (tid == 0)
                __hip_atomic_store(p1, c + 1, __ATOMIC_RELEASE, __HIP_MEMORY_SCOPE_AGENT);
        }
        return;
    }

    // ------------------- recurrence (role 0 = L0, role 2 = L1) ------------
    const float* wsrc = (role == 2) ? w_hh1 : w_hh0;
    const float* bsrc = (role == 2) ? b_hh1 : b_hh0;

    f16x2 wr[3][32];
#pragma unroll
    for (int G = 0; G < 3; G++) {
        const float2* w2 = (const float2*)(wsrc + (size_t)(g + 128 * G) * 128 + kh * 64);
#pragma unroll
        for (int i = 0; i < 32; i++) {
            float2 v = w2[i];
            wr[G][i] = (f16x2){(_Float16)v.x, (_Float16)v.y};
        }
    }
    const float bg0 = bsrc[g];
    const float bg1 = bsrc[g + 128];
    const float bg2 = bsrc[g + 256];

    if (tid < 128) hb[0][tid] = (_Float16)0.f;
    float h_own = 0.f;

    const float* gi_g = gi + (size_t)b * G3_ + g;
    float* y_g = ybuf + (size_t)b * H_ + g;

    // L1: gate prologue prefetch (rows 0,1) requires gi1 chunks 0,1 ready
    if (role == 2) {
        if (tid == 0) wait_ge(p1, 2);
        __syncthreads();
    }

    // prologue gi prefetch: t=0 -> A, t=1 -> B
    float irA = gi_g[0], izA = gi_g[128], innA = gi_g[256];
    const float* pp1 = gi_g + (size_t)(B_ * G3_);
    float irB = pp1[0], izB = pp1[128], innB = pp1[256];

    __syncthreads();  // hb[0] init visible

    for (int c = 0; c < NCH_; c++) {
        if (role == 2) {
            const int need = (c + 2 < NCH_) ? (c + 2) : NCH_;
            if (tid == 0) wait_ge(p1, need);
            __syncthreads();
        }
        const int t0 = c * CH_;
        for (int i = 0; i < CH_ / 2; i++) {
            const int t = t0 + 2 * i;
            GSTEPX(0, 1, irA, izA, innA, t,     t + 2)
            GSTEPX(1, 0, irB, izB, innB, t + 1, t + 3)
        }
        if (role == 0) {
            asm volatile("s_waitcnt vmcnt(0)" ::: "memory");  // y0 stores done
            __syncthreads();
            if (tid == 0)
                __hip_atomic_store(p0, (c + 1) * CH_, __ATOMIC_RELEASE, __HIP_MEMORY_SCOPE_AGENT);
        }
    }
}

// ---------------------------------------------------------------------------
// K5: out[b*T+t][c] = relu(fc_b[c] + dot(fc_w[c], y[t*B+b]))
// ---------------------------------------------------------------------------
__global__ __launch_bounds__(256, 2) void fc_relu(
    const float* __restrict__ y,     // [M,128]
    const float* __restrict__ fc_w,  // [32,128]
    const float* __restrict__ fc_b,  // [32]
    float* __restrict__ out)         // [B*T,32]
{
    const int tid = threadIdx.x;
    const int c = tid & 31;
    const int slot = tid >> 5;

    float4 wr[32];
    const float4* w4 = (const float4*)(fc_w + c * 128);
#pragma unroll
    for (int i = 0; i < 32; i++) wr[i] = w4[i];
    const float bc = fc_b[c];

    __shared__ __align__(16) float rows[8][128];

    for (int grp = blockIdx.x; grp < M_ / 8; grp += gridDim.x) {
        const int m0 = grp * 8;
        __syncthreads();
        for (int i = tid; i < 8 * 128; i += 256) {
            rows[i >> 7][i & 127] = y[(long)m0 * 128 + i];
        }
        __syncthreads();
        const float4* h4 = (const float4*)rows[slot];
        float a0 = bc, a1 = 0.f, a2 = 0.f, a3 = 0.f;
#pragma unroll
        for (int i = 0; i < 32; i += 4) {
            float4 h0 = h4[i], h1 = h4[i + 1], h2 = h4[i + 2], h3 = h4[i + 3];
            a0 = fmaf(wr[i].w, h0.w, fmaf(wr[i].z, h0.z, fmaf(wr[i].y, h0.y, fmaf(wr[i].x, h0.x, a0))));
            a1 = fmaf(wr[i+1].w, h1.w, fmaf(wr[i+1].z, h1.z, fmaf(wr[i+1].y, h1.y, fmaf(wr[i+1].x, h1.x, a1))));
            a2 = fmaf(wr[i+2].w, h2.w, fmaf(wr[i+2].z, h2.z, fmaf(wr[i+2].y, h2.y, fmaf(wr[i+2].x, h2.x, a2))));
            a3 = fmaf(wr[i+3].w, h3.w, fmaf(wr[i+3].z, h3.z, fmaf(wr[i+3].y, h3.y, fmaf(wr[i+3].x, h3.x, a3))));
        }
        float acc = (a0 + a1) + (a2 + a3);
        acc = fmaxf(acc, 0.f);
        const int m = m0 + slot;
        const int t = m >> 6;
        const int b = m & 63;
        out[((long)b * T_ + t) * C_ + c] = acc;
    }
}

// ---------------------------------------------------------------------------
extern "C" void kernel_launch(void* const* d_in, const int* in_sizes, int n_in,
                              void* d_out, int out_size, void* d_ws, size_t ws_size,
                              hipStream_t stream) {
    const int*   x     = (const int*)d_in[0];
    const float* emb   = (const float*)d_in[1];
    const float* w_ih0 = (const float*)d_in[2];
    const float* w_hh0 = (const float*)d_in[3];
    const float* b_ih0 = (const float*)d_in[4];
    const float* b_hh0 = (const float*)d_in[5];
    const float* w_ih1 = (const float*)d_in[6];
    const float* w_hh1 = (const float*)d_in[7];
    const float* b_ih1 = (const float*)d_in[8];
    const float* b_hh1 = (const float*)d_in[9];
    const float* fc_w  = (const float*)d_in[10];
    const float* fc_b  = (const float*)d_in[11];
    float* out = (float*)d_out;

    // workspace: gi [M,384] fp32 (201.3 MB, gi0 overwritten in-place by gi1)
    //          + ybuf [M,128] fp32 (67.1 MB, y0 then y1) = 268.4 MB
    float* gi   = (float*)d_ws;
    float* ybuf = (float*)((char*)d_ws + (size_t)M_ * G3_ * sizeof(float));

    // pipeline flags live at the start of d_out (overwritten by fc_relu later)
    hipMemsetAsync(d_out, 0, 128 * sizeof(int), stream);

    // layer 0 input gates (embedding gather fused)
    gates_gemm<true><<<512, 384, 0, stream>>>(emb, x, w_ih0, b_ih0, gi);
    // 3-stage pipelined recurrence: L0 | gi1-GEMM | L1
    gru_pipe<<<192, 256, 0, stream>>>(gi, w_hh0, b_hh0, w_ih1, b_ih1, w_hh1, b_hh1,
                                      ybuf, (int*)d_out);
    // FC + ReLU
    fc_relu<<<512, 256, 0, stream>>>(ybuf, fc_w, fc_b, out);
}